// Round 1
// baseline (104.589 us; speedup 1.0000x reference)
//
#include <hip/hip_runtime.h>
#include <hip/hip_bf16.h>

// Reference returns `inputs` unchanged (ScaleGrad.forward is identity; the
// counts/weights are only used in backward, which is not benched). So the
// kernel is a pure D2D copy of d_in[0] (float32, N*M = 16384*4096 elements)
// into d_out. Memory-bound: 512 MiB total traffic -> ~85us floor at 6.3 TB/s.

extern "C" void kernel_launch(void* const* d_in, const int* in_sizes, int n_in,
                              void* d_out, int out_size, void* d_ws, size_t ws_size,
                              hipStream_t stream) {
    const float* inputs = (const float*)d_in[0];
    float* out = (float*)d_out;
    size_t nbytes = (size_t)out_size * sizeof(float);
    hipMemcpyAsync(out, inputs, nbytes, hipMemcpyDeviceToDevice, stream);
}